// Round 11
// baseline (263.829 us; speedup 1.0000x reference)
//
#include <hip/hip_runtime.h>

#define TT 50
#define LL 512
#define BB 1024
#define START_TAG 48
#define STOP_TAG 49
#define S 64
#define NCH 8
#define LN2F 0.69314718056f
#define UP_THR 0x1p40f
#define DN_THR 0x1p-20f
#define SHF 48.0f

typedef __attribute__((ext_vector_type(4))) short bf16x4;
typedef __attribute__((ext_vector_type(4))) float f32x4;
typedef __attribute__((ext_vector_type(2))) float f32x2;

__device__ __forceinline__ f32x4 mfma16(bf16x4 a, bf16x4 b, f32x4 c) {
#if __has_builtin(__builtin_amdgcn_mfma_f32_16x16x16bf16_1k)
    return __builtin_amdgcn_mfma_f32_16x16x16bf16_1k(a, b, c, 0, 0, 0);
#else
    f32x4 d;
    asm("v_mfma_f32_16x16x16_bf16 %0, %1, %2, %3\n\ts_nop 7\n\ts_nop 1"
        : "=v"(d) : "v"(a), "v"(b), "v"(c));
    return d;
#endif
}
__device__ __forceinline__ unsigned int cvtpk(float lo, float hi) {
    unsigned int w;
    asm("v_cvt_pk_bf16_f32 %0, %1, %2" : "=v"(w) : "v"(lo), "v"(hi));
    return w;
}
__device__ __forceinline__ bf16x4 bits_to_bf(unsigned int lo, unsigned int hi) {
    union { unsigned int u[2]; bf16x4 v; } c; c.u[0] = lo; c.u[1] = hi; return c.v;
}
__device__ __forceinline__ bf16x4 make_bf4(float a, float b, float c, float d) {
    return bits_to_bf(cvtpk(a, b), cvtpk(c, d));
}
__device__ __forceinline__ float wsum(float v) {
#pragma unroll
    for (int o = 1; o < 64; o <<= 1) v += __shfl_xor(v, o);
    return v;
}
__device__ __forceinline__ float wavemax(float v) {
#pragma unroll
    for (int o = 1; o < 64; o <<= 1) v = fmaxf(v, __shfl_xor(v, o));
    return v;
}

// ---------------- block = one sequence: 8 chunk-matrix waves + 1 score wave --
// Chunk wave c computes P_c = Prod_{t in [max(1,64c), min(64c+64,len))} (D_t M)
// as a full 48x48 matrix (identity seed; empty range -> exact identity).
// All control flow is wave-uniform (one seq per wave): no per-column liveness.
__global__ __launch_bounds__(576) void crf_mat(
    const float* __restrict__ logits, const float* __restrict__ trans,
    const int* __restrict__ labels, const int* __restrict__ lens,
    float* __restrict__ nll)
{
    __shared__ float P[NCH][48][49];   // +1 pad: stride 49 coprime with 32 banks
    __shared__ float scL[NCH];
    __shared__ float sscore;
    __shared__ float vbuf[64];

    const int b    = blockIdx.x;
    const int wid  = threadIdx.x >> 6;
    const int lane = threadIdx.x & 63;
    const int len  = lens[b];
    const int col  = lane & 15, grp = lane >> 4;

    if (wid < NCH) {
        const int c = wid;

        // A = M tiles: A[T][Ck] reg j = exp(trans[16T+col][16Ck+4grp+j])  (R6-verified layout)
        bf16x4 A[3][3];
#pragma unroll
        for (int T = 0; T < 3; ++T)
#pragma unroll
            for (int Ck = 0; Ck < 3; ++Ck) {
                float v0 = __expf(trans[(16*T + col)*TT + (16*Ck + 4*grp + 0)]);
                float v1 = __expf(trans[(16*T + col)*TT + (16*Ck + 4*grp + 1)]);
                float v2 = __expf(trans[(16*T + col)*TT + (16*Ck + 4*grp + 2)]);
                float v3 = __expf(trans[(16*T + col)*TT + (16*Ck + 4*grp + 3)]);
                A[T][Ck] = make_bf4(v0, v1, v2, v3);
            }

        // X = I in B-operand layout: tile [Ck][N] reg j = X[16Ck+4grp+j][16N+col]
        bf16x4 Bt[3][3];
#pragma unroll
        for (int Ck = 0; Ck < 3; ++Ck)
#pragma unroll
            for (int N = 0; N < 3; ++N) {
                float v[4];
#pragma unroll
                for (int j = 0; j < 4; ++j)
                    v[j] = (Ck == N && (4*grp + j) == col) ? 1.0f : 0.0f;
                Bt[Ck][N] = make_bf4(v[0], v[1], v[2], v[3]);
            }

        const float* lpg = logits + (size_t)b * LL * TT + 4*grp;
        const int tstart = (c == 0) ? 1 : c * S;
        const int tend   = (c * S + S < len) ? (c * S + S) : len;

        float moff2 = 0.f, shNext = 0.f;
        const f32x4 kZ = {0.f, 0.f, 0.f, 0.f};

        for (int t = tstart; t < tend; ++t) {
            const float* p = lpg + (size_t)t * TT;
            f32x2 q0 = *(const f32x2*)(p);      f32x2 q1 = *(const f32x2*)(p + 2);
            f32x2 q2 = *(const f32x2*)(p + 16); f32x2 q3 = *(const f32x2*)(p + 18);
            f32x2 q4 = *(const f32x2*)(p + 32); f32x2 q5 = *(const f32x2*)(p + 34);
            f32x4 e[3];
            e[0] = (f32x4){__expf(fmaf(shNext, LN2F, q0.x)), __expf(fmaf(shNext, LN2F, q0.y)),
                           __expf(fmaf(shNext, LN2F, q1.x)), __expf(fmaf(shNext, LN2F, q1.y))};
            e[1] = (f32x4){__expf(fmaf(shNext, LN2F, q2.x)), __expf(fmaf(shNext, LN2F, q2.y)),
                           __expf(fmaf(shNext, LN2F, q3.x)), __expf(fmaf(shNext, LN2F, q3.y))};
            e[2] = (f32x4){__expf(fmaf(shNext, LN2F, q4.x)), __expf(fmaf(shNext, LN2F, q4.y)),
                           __expf(fmaf(shNext, LN2F, q5.x)), __expf(fmaf(shNext, LN2F, q5.y))};

            f32x4 Cv[3][3];
#pragma unroll
            for (int T = 0; T < 3; ++T)
#pragma unroll
                for (int N = 0; N < 3; ++N) {
                    Cv[T][N] = mfma16(A[T][0], Bt[0][N],
                               mfma16(A[T][1], Bt[1][N],
                               mfma16(A[T][2], Bt[2][N], kZ)));
                    Cv[T][N] *= e[T];   // D_t scales output rows 16T+4grp+j
                }
#pragma unroll
            for (int T = 0; T < 3; ++T)
#pragma unroll
                for (int N = 0; N < 3; ++N)
                    Bt[T][N] = make_bf4(Cv[T][N].x, Cv[T][N].y, Cv[T][N].z, Cv[T][N].w);

            moff2 -= shNext;     // shift applied this step (folded into e)
            shNext = 0.f;
            if ((t & 3) == 0) {  // wave-global rescale check every 4 steps
                float mx = 0.f;
#pragma unroll
                for (int T = 0; T < 3; ++T)
#pragma unroll
                    for (int N = 0; N < 3; ++N)
                        mx = fmaxf(mx, fmaxf(fmaxf(Cv[T][N].x, Cv[T][N].y),
                                             fmaxf(Cv[T][N].z, Cv[T][N].w)));
                mx = wavemax(mx);
                shNext = (mx > UP_THR) ? -SHF : ((mx < DN_THR) ? SHF : 0.f);
            }
        }

        // epilogue: unpack bf16 state, wave-normalize, write P + log-scale
        float X[3][3][4];
        float mx = 0.f;
#pragma unroll
        for (int Ck = 0; Ck < 3; ++Ck)
#pragma unroll
            for (int N = 0; N < 3; ++N) {
                union { bf16x4 v; unsigned int u[2]; } cc; cc.v = Bt[Ck][N];
                X[Ck][N][0] = __uint_as_float(cc.u[0] << 16);
                X[Ck][N][1] = __uint_as_float(cc.u[0] & 0xffff0000u);
                X[Ck][N][2] = __uint_as_float(cc.u[1] << 16);
                X[Ck][N][3] = __uint_as_float(cc.u[1] & 0xffff0000u);
#pragma unroll
                for (int j = 0; j < 4; ++j) mx = fmaxf(mx, X[Ck][N][j]);
            }
        mx = wavemax(mx);
        const float cm = fmaxf(mx, 1e-30f);
        const float r  = 1.0f / cm;
#pragma unroll
        for (int Ck = 0; Ck < 3; ++Ck)
#pragma unroll
            for (int N = 0; N < 3; ++N)
#pragma unroll
                for (int j = 0; j < 4; ++j)
                    P[c][16*Ck + 4*grp + j][16*N + col] = X[Ck][N][j] * r;
        if (lane == 0) scL[c] = moff2 * LN2F + __logf(cm);
    } else {
        // wid == 8: gold-path score (verified R8 logic)
        float acc = 0.f;
        for (int t = lane; t < len; t += 64) {
            const int lab = labels[b * LL + t];
            acc += logits[((size_t)b * LL + t) * TT + lab];
            const int prev = (t == 0) ? START_TAG : labels[b * LL + t - 1];
            acc += trans[lab * TT + prev];
        }
        if (lane == 0) acc += trans[STOP_TAG * TT + labels[b * LL + len - 1]];
        acc = wsum(acc);
        if (lane == 0) sscore = acc;
    }
    __syncthreads();

    if (wid == 0) {
        // v_0 = D_0 M e_start (exact t=0 seed), then chain the 8 chunk matrices
        float v = (lane < 48)
            ? __expf(trans[lane * TT + START_TAG] + logits[(size_t)b * LL * TT + lane])
            : 0.f;
        float m = fmaxf(wavemax(v), 1e-37f);
        float Slog = __logf(m);
        v *= (1.0f / m);

        for (int c = 0; c < NCH; ++c) {
            vbuf[lane] = v;   // lanes >= 48 write 0
            asm volatile("s_waitcnt lgkmcnt(0)" ::: "memory");
            __builtin_amdgcn_wave_barrier();
            float nv = 0.f;
            if (lane < 48) {
#pragma unroll 8
                for (int k = 0; k < 48; ++k)
                    nv = fmaf(P[c][lane][k], vbuf[k], nv);
            }
            asm volatile("s_waitcnt lgkmcnt(0)" ::: "memory");
            __builtin_amdgcn_wave_barrier();
            float mm = fmaxf(wavemax(nv), 1e-37f);
            v = nv * (1.0f / mm);
            Slog += scL[c] + __logf(mm);
        }
        float tv = (lane < 48) ? __expf(trans[STOP_TAG * TT + lane]) * v : 0.f;
        float ss = wsum(tv);
        if (lane == 0) nll[b] = __logf(fmaxf(ss, 1e-37f)) + Slog - sscore;
    }
}

// ---------------- final deterministic reduction ------------------------------
__global__ __launch_bounds__(1024) void crf_reduce(
    const float* __restrict__ nll, float* __restrict__ out)
{
    __shared__ float red[16];
    const int tid = threadIdx.x;
    float acc = nll[tid];
#pragma unroll
    for (int o = 32; o > 0; o >>= 1) acc += __shfl_xor(acc, o);
    if ((tid & 63) == 0) red[tid >> 6] = acc;
    __syncthreads();
    if (tid == 0) {
        float tot = 0.0f;
        for (int i = 0; i < 16; ++i) tot += red[i];
        out[0] = tot / (float)BB;
    }
}

extern "C" void kernel_launch(void* const* d_in, const int* in_sizes, int n_in,
                              void* d_out, int out_size, void* d_ws, size_t ws_size,
                              hipStream_t stream) {
    const float* logits = (const float*)d_in[0];
    const float* trans  = (const float*)d_in[1];
    const int*   labels = (const int*)d_in[2];
    const int*   lens   = (const int*)d_in[3];

    float* nll = (float*)d_ws;   // 4 KB only
    float* out = (float*)d_out;

    crf_mat<<<BB, 576, 0, stream>>>(logits, trans, labels, lens, nll);
    crf_reduce<<<1, 1024, 0, stream>>>(nll, out);
}